// Round 6
// baseline (196.552 us; speedup 1.0000x reference)
//
#include <hip/hip_runtime.h>
#include <stdint.h>

typedef _Float16 half8 __attribute__((ext_vector_type(8)));
typedef _Float16 half4 __attribute__((ext_vector_type(4)));
typedef float f32x4 __attribute__((ext_vector_type(4)));

constexpr int B = 2, L = 2048, S = 2048, H = 16, E = 64, D = 64;
constexpr int BM = 128;  // Q rows per workgroup (32 per wave)
constexpr int BN = 64;   // s rows per compute half-step
constexpr int TN = 128;  // s rows per staged tile (2 half-steps per barrier)
constexpr int NDT = S / TN;       // 16 staged tiles
constexpr int NHS = S / BN;       // 32 half-steps
constexpr float CS = 0.125f * 1.44269504089f;  // scale * log2(e)

// ws layout: Kh [bh][s][e] f16, 16B-chunk XOR-swizzled within each 128B row
//            (slot = chunk ^ (s&7)) | VTh [bh][d][s] f16, swizzled per 64-half
//            segment (slot = chunk ^ (d&7)) | Mh [l][s] f16 prescaled by CS (linear)
constexpr size_t KH_HALFS = (size_t)B * H * S * E;
constexpr size_t VT_HALFS = (size_t)B * H * D * S;
constexpr size_t MH_HALFS = (size_t)L * S;
constexpr size_t WS_NEED  = (KH_HALFS + VT_HALFS + MH_HALFS) * 2;  // 24 MB

// ============================================================================
// Pre-pass (verified in rounds 4/5; unchanged)
// ============================================================================
__global__ __launch_bounds__(256, 4)
void prep_kernel(const float* __restrict__ Kg, const float* __restrict__ Vg,
                 const float* __restrict__ Mg, _Float16* __restrict__ ws)
{
    _Float16* Kh  = ws;
    _Float16* VTh = ws + KH_HALFS;
    _Float16* Mh  = ws + KH_HALFS + VT_HALFS;
    const int tid = threadIdx.x;
    const int bid = blockIdx.x;

    if (bid < 2048) {
        // ---- K: [b][s][h][e] f32 -> [bh][s][slot] f16, slot = chunk^(s&7) ----
        const int idx = bid * 256 + tid;
        const int c   = idx & 7;
        const int s   = (idx >> 3) & 2047;
        const int bh  = idx >> 14;
        const int b   = bh >> 4, h = bh & 15;
        const float* src = Kg + ((size_t)(b * S + s)) * (H * E) + h * E + c * 8;
        const float4 v0 = *(const float4*)(src);
        const float4 v1 = *(const float4*)(src + 4);
        half8 o = {(_Float16)v0.x, (_Float16)v0.y, (_Float16)v0.z, (_Float16)v0.w,
                   (_Float16)v1.x, (_Float16)v1.y, (_Float16)v1.z, (_Float16)v1.w};
        *(half8*)(Kh + (((size_t)bh * S + s) << 6) + ((c ^ (s & 7)) * 8)) = o;
    } else if (bid < 4096) {
        // ---- mask: f32 -> f16 * CS, linear ----
        const size_t idx = (size_t)(bid - 2048) * 256 + tid;
        const float* src = Mg + idx * 8;
        const float4 v0 = *(const float4*)(src);
        const float4 v1 = *(const float4*)(src + 4);
        half8 o = {(_Float16)(v0.x*CS), (_Float16)(v0.y*CS), (_Float16)(v0.z*CS),
                   (_Float16)(v0.w*CS), (_Float16)(v1.x*CS), (_Float16)(v1.y*CS),
                   (_Float16)(v1.z*CS), (_Float16)(v1.w*CS)};
        *(half8*)(Mh + idx * 8) = o;
    } else {
        // ---- V: [b][s][h][d] f32 -> [bh][d][seg slot] f16, slot = chunk^(d&7) ----
        __shared__ _Float16 tile[64][72];
        const int bid2 = bid - 4096;
        const int sblk = bid2 & 31;
        const int h    = (bid2 >> 5) & 15;
        const int b    = bid2 >> 9;
        const int ts = tid >> 4, d4 = (tid & 15) << 2;
        #pragma unroll
        for (int ii = 0; ii < 4; ++ii) {
            const int sl = ts + ii * 16;
            const float4 v = *(const float4*)(Vg + ((size_t)(b * S + sblk*64 + sl)) * (H * D) + h * D + d4);
            #pragma unroll
            for (int j = 0; j < 4; ++j)
                tile[d4 + j][sl] = (_Float16)((&v.x)[j]);
        }
        __syncthreads();
        const int d = tid >> 2, cp = tid & 3;
        _Float16* drow = VTh + (((size_t)(b * H + h) * D + d) << 11) + sblk * 64;
        #pragma unroll
        for (int k = 0; k < 2; ++k) {
            const int chunk = cp * 2 + k;
            half8 o;
            #pragma unroll
            for (int j = 0; j < 8; ++j) o[j] = tile[d][chunk * 8 + j];
            *(half8*)(drow + ((chunk ^ (d & 7)) * 8)) = o;
        }
    }
}

// ============================================================================
// Main kernel: 128-row double-buffered DMA tiles, ONE barrier per 2 half-steps.
// sP is wave-private and reused across half-steps (intra-wave lgkm ordering).
// ============================================================================
__device__ __forceinline__ void gload16(const _Float16* g, const _Float16* l) {
    __builtin_amdgcn_global_load_lds(
        (const __attribute__((address_space(1))) uint32_t*)(uintptr_t)(g),
        (__attribute__((address_space(3))) uint32_t*)(uintptr_t)(l),
        16, 0, 0);
}

// Stage a full 128-s tile: wave w -> K rows [32w,32w+32), V d-rows [16w,16w+16).
#define STAGE(BUF, S0)                                                            \
{                                                                                 \
    _Pragma("unroll")                                                             \
    for (int ii = 0; ii < 4; ++ii) {                                              \
        const int kr = wave * 32 + ii * 8;                                        \
        gload16(kh_bh + ((size_t)((S0) + kr + (lane >> 3)) << 6) + (lane & 7)*8,  \
                &sK[BUF][kr][0]);                                                 \
    }                                                                             \
    _Pragma("unroll")                                                             \
    for (int ii = 0; ii < 4; ++ii) {                                              \
        const int dr = wave * 16 + ii * 4;                                        \
        gload16(vt_bh + ((size_t)(dr + (lane >> 4)) << 11) + (S0) + (lane & 15)*8,\
                &sV[BUF][dr][0]);                                                 \
    }                                                                             \
}

// One 64-s compute half-step on staged buffer BUF, half HS (0/1).
// MC: this step's mask regs; MN: prefetch dest for step TH+1. No barrier inside.
#define HALF_STEP(BUF, HS, MC, MN, TH)                                                      \
{                                                                                           \
    /* S^T = K Q^T; K-frags from swizzled sK, each feeds both q-groups */                   \
    f32x4 sf[2][4];                                                                         \
    __builtin_amdgcn_s_setprio(1);                                                          \
    _Pragma("unroll")                                                                       \
    for (int nt = 0; nt < 4; ++nt) {                                                        \
        half8 kf0 = *(const half8*)&sK[BUF][(HS)*64 + nt*16 + lq][((    quad) ^ (lq & 7)) * 8];\
        half8 kf1 = *(const half8*)&sK[BUF][(HS)*64 + nt*16 + lq][((4 + quad) ^ (lq & 7)) * 8];\
        _Pragma("unroll")                                                                   \
        for (int g = 0; g < 2; ++g) {                                                       \
            f32x4 acc = (f32x4){0.f, 0.f, 0.f, 0.f};                                        \
            acc = __builtin_amdgcn_mfma_f32_16x16x32_f16(kf0, qf[g][0], acc, 0, 0, 0);      \
            acc = __builtin_amdgcn_mfma_f32_16x16x32_f16(kf1, qf[g][1], acc, 0, 0, 0);      \
            sf[g][nt] = acc;                                                                \
        }                                                                                   \
    }                                                                                       \
    __builtin_amdgcn_s_setprio(0);                                                          \
    /* softmax: p = exp2(sf + mask); swizzled b64 stores to wave-private sP */              \
    _Pragma("unroll")                                                                       \
    for (int g = 0; g < 2; ++g) {                                                           \
        _Float16* prow = &sP[wave][g*16 + lq][0];                                           \
        _Pragma("unroll")                                                                   \
        for (int nt = 0; nt < 4; ++nt) {                                                    \
            half4 hp;                                                                       \
            _Pragma("unroll")                                                               \
            for (int r = 0; r < 4; ++r) {                                                   \
                float lg = sf[g][nt][r] + (float)MC[g*4 + nt][r];                           \
                float p  = __builtin_amdgcn_exp2f(lg);                                      \
                lsum[g] += p;                                                               \
                hp[r] = (_Float16)p;                                                        \
            }                                                                               \
            *(half4*)(prow + (((2*nt + (quad >> 1)) ^ (lq & 7)) * 8 + (quad & 1) * 4)) = hp;\
        }                                                                                   \
    }                                                                                       \
    /* mask prefetch for half-step TH+1 (L2/L3-resident) */                                 \
    if ((TH) + 1 < NHS) {                                                                   \
        const int s1_ = ((TH) + 1) * BN;                                                    \
        _Pragma("unroll")                                                                   \
        for (int g = 0; g < 2; ++g)                                                         \
            _Pragma("unroll")                                                               \
            for (int nt = 0; nt < 4; ++nt)                                                  \
                MN[g*4 + nt] = *(const half4*)(mrow0 + ((size_t)g << 15)                    \
                                               + s1_ + nt*16 + quad*4);                     \
    }                                                                                       \
    /* O += P V from swizzled sP / sV */                                                    \
    __builtin_amdgcn_s_setprio(1);                                                          \
    _Pragma("unroll")                                                                       \
    for (int ks = 0; ks < 2; ++ks) {                                                        \
        half8 pf0 = *(const half8*)&sP[wave][     lq][((4*ks + quad) ^ (lq & 7)) * 8];      \
        half8 pf1 = *(const half8*)&sP[wave][16 + lq][((4*ks + quad) ^ (lq & 7)) * 8];      \
        _Pragma("unroll")                                                                   \
        for (int dt = 0; dt < 4; ++dt) {                                                    \
            half8 vf = *(const half8*)&sV[BUF][dt*16 + lq][(HS)*64 + ((4*ks + quad) ^ (lq & 7)) * 8];\
            oacc[0][dt] = __builtin_amdgcn_mfma_f32_16x16x32_f16(pf0, vf, oacc[0][dt],0,0,0);\
            oacc[1][dt] = __builtin_amdgcn_mfma_f32_16x16x32_f16(pf1, vf, oacc[1][dt],0,0,0);\
        }                                                                                   \
    }                                                                                       \
    __builtin_amdgcn_s_setprio(0);                                                          \
}

__global__ __launch_bounds__(256, 2)
void fa4_kernel(const float* __restrict__ Qg, const _Float16* __restrict__ ws,
                float* __restrict__ Og)
{
    __shared__ _Float16 sK[2][TN][64];   // 32 KB, double-buffered, DMA-filled
    __shared__ _Float16 sV[2][D][TN];    // 32 KB
    __shared__ _Float16 sP[4][32][64];   // 16 KB, wave-private, reused per half-step

    const _Float16* Kh  = ws;
    const _Float16* VTh = ws + KH_HALFS;
    const _Float16* Mh  = ws + KH_HALFS + VT_HALFS;

    const int tid  = threadIdx.x;
    const int wave = tid >> 6;
    const int lane = tid & 63;
    const int quad = lane >> 4;
    const int lq   = lane & 15;

    // XCD-aware decode: WG i -> XCD i%8; each XCD owns 4 (b,h) -> f16 K/V = 2 MB < L2.
    const int i  = blockIdx.x;             // grid = 512
    const int bh = (i & 7) * 4 + ((i >> 3) & 3);
    const int qb = i >> 5;
    const int b  = bh >> 4;
    const int h  = bh & 15;
    const int q0 = qb * BM;

    const int rowStride = H * E;
    const size_t qbase = ((size_t)b * L) * rowStride + h * E;

    const _Float16* kh_bh = Kh  + ((size_t)(b * H + h) << 17);
    const _Float16* vt_bh = VTh + ((size_t)(b * H + h) << 17);
    const _Float16* mrow0 = Mh  + ((size_t)(q0 + wave * 32 + lq) << 11);

    // ---- Q fragments (2 q-groups), prescaled by CS ----
    half8 qf[2][2];
    #pragma unroll
    for (int g = 0; g < 2; ++g) {
        const float* qp = Qg + qbase + (size_t)(q0 + wave*32 + g*16 + lq) * rowStride + quad*8;
        #pragma unroll
        for (int ks = 0; ks < 2; ++ks)
            #pragma unroll
            for (int j = 0; j < 8; ++j)
                qf[g][ks][j] = (_Float16)(qp[ks*32 + j] * CS);
    }

    float lsum[2] = {0.f, 0.f};
    f32x4 oacc[2][4];
    #pragma unroll
    for (int g = 0; g < 2; ++g)
        #pragma unroll
        for (int dt = 0; dt < 4; ++dt) oacc[g][dt] = (f32x4){0.f, 0.f, 0.f, 0.f};

    half4 mA[8], mB[8];

    // ---- prologue: DMA tile 0 into buf0; mask half-step 0 -> regs ----
    STAGE(0, 0)
    #pragma unroll
    for (int g = 0; g < 2; ++g)
        #pragma unroll
        for (int nt = 0; nt < 4; ++nt)
            mA[g*4 + nt] = *(const half4*)(mrow0 + ((size_t)g << 15) + nt*16 + quad*4);
    __syncthreads();

    // NDT = 16 (even): unrolled buffer pair per loop iteration.
    for (int t2 = 0; t2 < NDT; t2 += 2) {
        STAGE(1, (t2 + 1) * TN)
        HALF_STEP(0, 0, mA, mB, 2*t2)
        HALF_STEP(0, 1, mB, mA, 2*t2 + 1)
        __syncthreads();   // drains DMA for buf1; orders buf0 reads vs next overwrite
        if (t2 + 2 < NDT) STAGE(0, (t2 + 2) * TN)
        HALF_STEP(1, 0, mA, mB, 2*t2 + 2)
        HALF_STEP(1, 1, mB, mA, 2*t2 + 3)
        if (t2 + 2 < NDT) __syncthreads();
    }

    // ---- epilogue per q-group: l reduce across quads, O /= l, store fp32 ----
    #pragma unroll
    for (int g = 0; g < 2; ++g) {
        float l = lsum[g];
        l += __shfl_xor(l, 16);
        l += __shfl_xor(l, 32);
        #pragma unroll
        for (int r = 0; r < 4; ++r) {
            float l_bc = __shfl(l, quad*4 + r, 16);
            float inv = 1.f / l_bc;
            float* orow = Og + qbase + (size_t)(q0 + wave*32 + g*16 + quad*4 + r) * rowStride;
            #pragma unroll
            for (int dt = 0; dt < 4; ++dt)
                orow[dt*16 + lq] = oacc[g][dt][r] * inv;
        }
    }
}

// ============================================================================
// Fallback (round-3 kernel, verified 103 us) for ws_size < WS_NEED.
// ============================================================================
constexpr int LDT = 72;

__global__ __launch_bounds__(256, 2)
void fa_fb_kernel(const float* __restrict__ Qg, const float* __restrict__ Kg,
                  const float* __restrict__ Vg, const float* __restrict__ Mg,
                  float* __restrict__ Og)
{
    __shared__ _Float16 sK[BN][LDT];
    __shared__ _Float16 sV[D][LDT];
    __shared__ _Float16 sP[4][32][LDT];

    const int tid  = threadIdx.x;
    const int wave = tid >> 6;
    const int lane = tid & 63;
    const int quad = lane >> 4;
    const int lq   = lane & 15;

    const int i  = blockIdx.x;
    const int bh = (i & 7) * 4 + ((i >> 3) & 3);
    const int qb = i >> 5;
    const int b  = bh >> 4;
    const int h  = bh & 15;
    const int q0 = qb * BM;

    const int rowStride = H * E;
    const size_t qbase = ((size_t)b * L) * rowStride + h * E;
    const size_t kbase = ((size_t)b * S) * rowStride + h * E;

    half8 qf[2][2];
    #pragma unroll
    for (int g = 0; g < 2; ++g) {
        const float* qp = Qg + qbase + (size_t)(q0 + wave*32 + g*16 + lq) * rowStride + quad*8;
        #pragma unroll
        for (int ks = 0; ks < 2; ++ks)
            #pragma unroll
            for (int j = 0; j < 8; ++j)
                qf[g][ks][j] = (_Float16)(qp[ks*32 + j] * CS);
    }

    const float* mrow0 = Mg + (size_t)(q0 + wave*32 + lq) * S;

    float lsum[2] = {0.f, 0.f};
    f32x4 oacc[2][4];
    #pragma unroll
    for (int g = 0; g < 2; ++g)
        #pragma unroll
        for (int dt = 0; dt < 4; ++dt) oacc[g][dt] = (f32x4){0.f, 0.f, 0.f, 0.f};

    const int db = tid & 15;
    const int sb = tid >> 4;
    const float* vbase = Vg + kbase + (size_t)(sb*4) * rowStride + db*4;
    const float* krow  = Kg + kbase + (size_t)(tid >> 4) * rowStride + (tid & 15)*4;
    const int voff = (((sb >> 1) ^ (db >> 1)) << 3) + ((sb & 1) << 2);

    float4 kreg[4], vreg[4], mreg[2][4];

    #pragma unroll
    for (int ii = 0; ii < 4; ++ii)
        kreg[ii] = *(const float4*)(krow + (size_t)(ii*16) * rowStride);
    #pragma unroll
    for (int j = 0; j < 4; ++j)
        vreg[j] = *(const float4*)(vbase + (size_t)j * rowStride);
    #pragma unroll
    for (int g = 0; g < 2; ++g)
        #pragma unroll
        for (int nt = 0; nt < 4; ++nt)
            mreg[g][nt] = *(const float4*)(mrow0 + (size_t)g*16*S + nt*16 + quad*4);

    #pragma unroll
    for (int ii = 0; ii < 4; ++ii) {
        half4 hk = {(_Float16)kreg[ii].x, (_Float16)kreg[ii].y,
                    (_Float16)kreg[ii].z, (_Float16)kreg[ii].w};
        *(half4*)&sK[(tid >> 4) + ii*16][(tid & 15)*4] = hk;
    }
    #pragma unroll
    for (int j = 0; j < 4; ++j) {
        half4 hv = { (_Float16)((&vreg[0].x)[j]), (_Float16)((&vreg[1].x)[j]),
                     (_Float16)((&vreg[2].x)[j]), (_Float16)((&vreg[3].x)[j]) };
        *(half4*)&sV[db*4 + j][voff] = hv;
    }
    __syncthreads();

    for (int t = 0; t < NHS; ++t) {
        if (t + 1 < NHS) {
            const int s1 = (t + 1) * BN;
            #pragma unroll
            for (int ii = 0; ii < 4; ++ii)
                kreg[ii] = *(const float4*)(krow + (size_t)(s1 + ii*16) * rowStride);
            #pragma unroll
            for (int j = 0; j < 4; ++j)
                vreg[j] = *(const float4*)(vbase + (size_t)(s1 + j) * rowStride);
        }

        f32x4 sf[2][4];
        __builtin_amdgcn_s_setprio(1);
        #pragma unroll
        for (int nt = 0; nt < 4; ++nt) {
            half8 kf0 = *(const half8*)&sK[nt*16 + lq][ 0 + quad*8];
            half8 kf1 = *(const half8*)&sK[nt*16 + lq][32 + quad*8];
            #pragma unroll
            for (int g = 0; g < 2; ++g) {
                f32x4 acc = (f32x4){0.f, 0.f, 0.f, 0.f};
                acc = __builtin_amdgcn_mfma_f32_16x16x32_f16(kf0, qf[g][0], acc, 0, 0, 0);
                acc = __builtin_amdgcn_mfma_f32_16x16x32_f16(kf1, qf[g][1], acc, 0, 0, 0);
                sf[g][nt] = acc;
            }
        }
        __builtin_amdgcn_s_setprio(0);

        #pragma unroll
        for (int g = 0; g < 2; ++g)
            #pragma unroll
            for (int nt = 0; nt < 4; ++nt) {
                half4 hp;
                #pragma unroll
                for (int r = 0; r < 4; ++r) {
                    float lg = fmaf((&mreg[g][nt].x)[r], CS, sf[g][nt][r]);
                    float p  = __builtin_amdgcn_exp2f(lg);
                    lsum[g] += p;
                    hp[r] = (_Float16)p;
                }
                *(half4*)&sP[wave][g*16 + lq][nt*16 + quad*4] = hp;
            }

        if (t + 1 < NHS) {
            const int s1 = (t + 1) * BN;
            #pragma unroll
            for (int g = 0; g < 2; ++g)
                #pragma unroll
                for (int nt = 0; nt < 4; ++nt)
                    mreg[g][nt] = *(const float4*)(mrow0 + (size_t)g*16*S + s1 + nt*16 + quad*4);
        }

        __builtin_amdgcn_s_setprio(1);
        #pragma unroll
        for (int ks = 0; ks < 2; ++ks) {
            half8 pf0 = *(const half8*)&sP[wave][ 0 + lq][ks*32 + quad*8];
            half8 pf1 = *(const half8*)&sP[wave][16 + lq][ks*32 + quad*8];
            #pragma unroll
            for (int dt = 0; dt < 4; ++dt) {
                const int vrow = dt*16 + lq;
                const int phys = (ks*4 + quad) ^ ((vrow >> 3) & 7);
                half8 vf = *(const half8*)&sV[vrow][phys << 3];
                oacc[0][dt] = __builtin_amdgcn_mfma_f32_16x16x32_f16(pf0, vf, oacc[0][dt], 0, 0, 0);
                oacc[1][dt] = __builtin_amdgcn_mfma_f32_16x16x32_f16(pf1, vf, oacc[1][dt], 0, 0, 0);
            }
        }
        __builtin_amdgcn_s_setprio(0);

        if (t + 1 < NHS) {
            __syncthreads();
            #pragma unroll
            for (int ii = 0; ii < 4; ++ii) {
                half4 hk = {(_Float16)kreg[ii].x, (_Float16)kreg[ii].y,
                            (_Float16)kreg[ii].z, (_Float16)kreg[ii].w};
                *(half4*)&sK[(tid >> 4) + ii*16][(tid & 15)*4] = hk;
            }
            #pragma unroll
            for (int j = 0; j < 4; ++j) {
                half4 hv = { (_Float16)((&vreg[0].x)[j]), (_Float16)((&vreg[1].x)[j]),
                             (_Float16)((&vreg[2].x)[j]), (_Float16)((&vreg[3].x)[j]) };
                *(half4*)&sV[db*4 + j][voff] = hv;
            }
            __syncthreads();
        }
    }

    #pragma unroll
    for (int g = 0; g < 2; ++g) {
        float l = lsum[g];
        l += __shfl_xor(l, 16);
        l += __shfl_xor(l, 32);
        #pragma unroll
        for (int r = 0; r < 4; ++r) {
            float l_bc = __shfl(l, quad*4 + r, 16);
            float inv = 1.f / l_bc;
            float* orow = Og + qbase + (size_t)(q0 + wave*32 + g*16 + quad*4 + r) * rowStride;
            #pragma unroll
            for (int dt = 0; dt < 4; ++dt)
                orow[dt*16 + lq] = oacc[g][dt][r] * inv;
        }
    }
}

extern "C" void kernel_launch(void* const* d_in, const int* in_sizes, int n_in,
                              void* d_out, int out_size, void* d_ws, size_t ws_size,
                              hipStream_t stream) {
    const float* Qg = (const float*)d_in[0];
    const float* Kg = (const float*)d_in[1];
    const float* Vg = (const float*)d_in[2];
    const float* Mg = (const float*)d_in[3];
    float* Og = (float*)d_out;

    if (ws_size >= WS_NEED && d_ws != nullptr) {
        _Float16* ws = (_Float16*)d_ws;
        prep_kernel<<<dim3(2048 + 2048 + 1024), 256, 0, stream>>>(Kg, Vg, Mg, ws);
        fa4_kernel<<<dim3((L / BM) * B * H), 256, 0, stream>>>(Qg, ws, Og);
    } else {
        fa_fb_kernel<<<dim3((L / BM) * B * H), 256, 0, stream>>>(Qg, Kg, Vg, Mg, Og);
    }
}

// Round 11
// 176.913 us; speedup vs baseline: 1.1110x; 1.1110x over previous
//
#include <hip/hip_runtime.h>

typedef _Float16 half8 __attribute__((ext_vector_type(8)));
typedef _Float16 half4 __attribute__((ext_vector_type(4)));
typedef float f32x4 __attribute__((ext_vector_type(4)));

constexpr int B = 2, L = 2048, S = 2048, H = 16, E = 64, D = 64;
constexpr int BM = 128;  // Q rows per workgroup (32 per wave: 2x MFMA per LDS read)
constexpr int BN = 64;   // K/V rows per iteration
constexpr int LDT = 72;  // f16 leading dim: 36-dword rows, 16B-aligned
constexpr int NTI = S / BN;

__global__ __launch_bounds__(256, 2)
void fa_kernel(const float* __restrict__ Qg, const float* __restrict__ Kg,
               const float* __restrict__ Vg, const float* __restrict__ Mg,
               float* __restrict__ Og)
{
    __shared__ _Float16 sK[BN][LDT];     // K tile [s][e]
    __shared__ _Float16 sV[D][LDT];      // V^T [d][s]; 16B chunk swizzle: phys = cl ^ ((d>>3)&7)
    __shared__ _Float16 sP[4][32][LDT];  // per-wave P [qrow 0..31][s]

    const int tid  = threadIdx.x;
    const int wave = tid >> 6;
    const int lane = tid & 63;
    const int quad = lane >> 4;
    const int lq   = lane & 15;

    // XCD-aware decode: WG i lands on XCD i%8; each XCD owns 4 (b,h) -> K/V set = 4 MB = L2.
    const int i  = blockIdx.x;             // grid = 512
    const int bh = (i & 7) * 4 + ((i >> 3) & 3);
    const int qb = i >> 5;
    const int b  = bh >> 4;
    const int h  = bh & 15;
    const int q0 = qb * BM;

    const int rowStride = H * E;  // 1024 floats
    const size_t qbase = ((size_t)b * L) * rowStride + h * E;
    const size_t kbase = ((size_t)b * S) * rowStride + h * E;

    const float cS = 0.125f * 1.44269504089f;  // scale*log2(e); fixed-shift exp2 softmax

    // ---- Q fragments for 2 q-groups, prescaled (B-operand: n=q=lq, k=e=ks*32+quad*8+j) ----
    half8 qf[2][2];
    #pragma unroll
    for (int g = 0; g < 2; ++g) {
        const float* qp = Qg + qbase + (size_t)(q0 + wave*32 + g*16 + lq) * rowStride + quad*8;
        #pragma unroll
        for (int ks = 0; ks < 2; ++ks)
            #pragma unroll
            for (int j = 0; j < 8; ++j)
                qf[g][ks][j] = (_Float16)(qp[ks*32 + j] * cS);
    }

    const float* mrow0 = Mg + (size_t)(q0 + wave*32 + lq) * S;  // g offset: +16*S

    float lsum[2] = {0.f, 0.f};
    f32x4 oacc[2][4];
    #pragma unroll
    for (int g = 0; g < 2; ++g)
        #pragma unroll
        for (int dt = 0; dt < 4; ++dt) oacc[g][dt] = (f32x4){0.f, 0.f, 0.f, 0.f};

    // staging decompositions (256 threads stage the 64x64 K and V tiles)
    const int db = tid & 15;
    const int sb = tid >> 4;
    const float* vbase = Vg + kbase + (size_t)(sb*4) * rowStride + db*4;
    const float* krow  = Kg + kbase + (size_t)(tid >> 4) * rowStride + (tid & 15)*4;
    const int voff = (((sb >> 1) ^ (db >> 1)) << 3) + ((sb & 1) << 2);

    // async-STAGE pipeline regs: tile t+1 lives here while tile t computes
    float4 kreg[4], vreg[4], mreg[2][4];

    // ---- prologue: load + stage tile 0, prefetch mask tile 0 ----
    #pragma unroll
    for (int ii = 0; ii < 4; ++ii)
        kreg[ii] = *(const float4*)(krow + (size_t)(ii*16) * rowStride);
    #pragma unroll
    for (int j = 0; j < 4; ++j)
        vreg[j] = *(const float4*)(vbase + (size_t)j * rowStride);
    #pragma unroll
    for (int g = 0; g < 2; ++g)
        #pragma unroll
        for (int nt = 0; nt < 4; ++nt)
            mreg[g][nt] = *(const float4*)(mrow0 + (size_t)g*16*S + nt*16 + quad*4);

    #pragma unroll
    for (int ii = 0; ii < 4; ++ii) {
        half4 hk = {(_Float16)kreg[ii].x, (_Float16)kreg[ii].y,
                    (_Float16)kreg[ii].z, (_Float16)kreg[ii].w};
        *(half4*)&sK[(tid >> 4) + ii*16][(tid & 15)*4] = hk;
    }
    #pragma unroll
    for (int j = 0; j < 4; ++j) {
        half4 hv = { (_Float16)((&vreg[0].x)[j]), (_Float16)((&vreg[1].x)[j]),
                     (_Float16)((&vreg[2].x)[j]), (_Float16)((&vreg[3].x)[j]) };
        *(half4*)&sV[db*4 + j][voff] = hv;
    }
    __syncthreads();

    for (int t = 0; t < NTI; ++t) {
        // ---- prefetch K/V tile t+1 into regs: latency hides under this tile's compute ----
        if (t + 1 < NTI) {
            const int s1 = (t + 1) * BN;
            #pragma unroll
            for (int ii = 0; ii < 4; ++ii)
                kreg[ii] = *(const float4*)(krow + (size_t)(s1 + ii*16) * rowStride);
            #pragma unroll
            for (int j = 0; j < 4; ++j)
                vreg[j] = *(const float4*)(vbase + (size_t)(s1 + j) * rowStride);
        }

        // ---- S^T = K Q^T (C: row=s, col=q=lq); each K-frag feeds BOTH q-groups ----
        f32x4 sf[2][4];
        __builtin_amdgcn_s_setprio(1);
        #pragma unroll
        for (int nt = 0; nt < 4; ++nt) {
            half8 kf0 = *(const half8*)&sK[nt*16 + lq][ 0 + quad*8];
            half8 kf1 = *(const half8*)&sK[nt*16 + lq][32 + quad*8];
            #pragma unroll
            for (int g = 0; g < 2; ++g) {
                f32x4 acc = (f32x4){0.f, 0.f, 0.f, 0.f};
                acc = __builtin_amdgcn_mfma_f32_16x16x32_f16(kf0, qf[g][0], acc, 0, 0, 0);
                acc = __builtin_amdgcn_mfma_f32_16x16x32_f16(kf1, qf[g][1], acc, 0, 0, 0);
                sf[g][nt] = acc;
            }
        }
        __builtin_amdgcn_s_setprio(0);

        // ---- p = exp2(logit + mask*cS); accumulate l; packed b64 stores to sP ----
        #pragma unroll
        for (int g = 0; g < 2; ++g)
            #pragma unroll
            for (int nt = 0; nt < 4; ++nt) {
                half4 hp;
                #pragma unroll
                for (int r = 0; r < 4; ++r) {
                    float lg = fmaf((&mreg[g][nt].x)[r], cS, sf[g][nt][r]);
                    float p  = __builtin_amdgcn_exp2f(lg);
                    lsum[g] += p;
                    hp[r] = (_Float16)p;
                }
                *(half4*)&sP[wave][g*16 + lq][nt*16 + quad*4] = hp;
            }

        // ---- prefetch mask tile t+1 (L3-resident): hides under PV + staging ----
        if (t + 1 < NTI) {
            const int s1 = (t + 1) * BN;
            #pragma unroll
            for (int g = 0; g < 2; ++g)
                #pragma unroll
                for (int nt = 0; nt < 4; ++nt)
                    mreg[g][nt] = *(const float4*)(mrow0 + (size_t)g*16*S + s1 + nt*16 + quad*4);
        }

        // ---- O += P V : each V-frag feeds BOTH q-groups ----
        __builtin_amdgcn_s_setprio(1);
        #pragma unroll
        for (int ks = 0; ks < 2; ++ks) {
            half8 pf0 = *(const half8*)&sP[wave][ 0 + lq][ks*32 + quad*8];
            half8 pf1 = *(const half8*)&sP[wave][16 + lq][ks*32 + quad*8];
            #pragma unroll
            for (int dt = 0; dt < 4; ++dt) {
                const int vrow = dt*16 + lq;
                const int phys = (ks*4 + quad) ^ ((vrow >> 3) & 7);
                half8 vf = *(const half8*)&sV[vrow][phys << 3];
                oacc[0][dt] = __builtin_amdgcn_mfma_f32_16x16x32_f16(pf0, vf, oacc[0][dt], 0, 0, 0);
                oacc[1][dt] = __builtin_amdgcn_mfma_f32_16x16x32_f16(pf1, vf, oacc[1][dt], 0, 0, 0);
            }
        }
        __builtin_amdgcn_s_setprio(0);

        // ---- write-late: convert prefetched regs -> LDS for tile t+1 ----
        if (t + 1 < NTI) {
            __syncthreads();   // B2: all sK/sV reads for tile t done
            #pragma unroll
            for (int ii = 0; ii < 4; ++ii) {
                half4 hk = {(_Float16)kreg[ii].x, (_Float16)kreg[ii].y,
                            (_Float16)kreg[ii].z, (_Float16)kreg[ii].w};
                *(half4*)&sK[(tid >> 4) + ii*16][(tid & 15)*4] = hk;
            }
            #pragma unroll
            for (int j = 0; j < 4; ++j) {
                half4 hv = { (_Float16)((&vreg[0].x)[j]), (_Float16)((&vreg[1].x)[j]),
                             (_Float16)((&vreg[2].x)[j]), (_Float16)((&vreg[3].x)[j]) };
                *(half4*)&sV[db*4 + j][voff] = hv;
            }
            __syncthreads();   // B1: tile t+1 staged and visible
        }
    }

    // ---- epilogue per q-group: l reduction across quads, O /= l, store fp32 ----
    #pragma unroll
    for (int g = 0; g < 2; ++g) {
        float l = lsum[g];
        l += __shfl_xor(l, 16);
        l += __shfl_xor(l, 32);
        #pragma unroll
        for (int r = 0; r < 4; ++r) {
            float l_bc = __shfl(l, quad*4 + r, 16);
            float inv = 1.f / l_bc;
            float* orow = Og + qbase + (size_t)(q0 + wave*32 + g*16 + quad*4 + r) * rowStride;
            #pragma unroll
            for (int dt = 0; dt < 4; ++dt)
                orow[dt*16 + lq] = oacc[g][dt][r] * inv;
        }
    }
}

extern "C" void kernel_launch(void* const* d_in, const int* in_sizes, int n_in,
                              void* d_out, int out_size, void* d_ws, size_t ws_size,
                              hipStream_t stream) {
    const float* Qg = (const float*)d_in[0];
    const float* Kg = (const float*)d_in[1];
    const float* Vg = (const float*)d_in[2];
    const float* Mg = (const float*)d_in[3];
    float* Og = (float*)d_out;
    dim3 grid((L / BM) * B * H);   // 512 WGs = exactly 2 per CU
    fa_kernel<<<grid, 256, 0, stream>>>(Qg, Kg, Vg, Mg, Og);
}